// Round 13
// baseline (146.987 us; speedup 1.0000x reference)
//
#include <hip/hip_runtime.h>
#include <math.h>

#define N_ 32
#define C_ 512
#define CR_ 64
#define HW_ 3136
#define HW4_ 784
constexpr float EPS = 1e-5f;

typedef float f4 __attribute__((ext_vector_type(4)));

#define LD_A(p)   __hip_atomic_load((p), __ATOMIC_RELAXED, __HIP_MEMORY_SCOPE_AGENT)
#define ST_A(p,v) __hip_atomic_store((p), (v), __ATOMIC_RELAXED, __HIP_MEMORY_SCOPE_AGENT)

// ---------------- Kernel A: pool + last-arrival gate (RELAXED protocol) ----------------
// One block per (n,c) row. Writer ordering: ST_A(pooled) -> s_waitcnt vmcnt(0)
// -> RELAXED fetch_add. The 512th arrival therefore sees all pooled stores
// complete. No acquire/release cache maintenance, no waiting, ever.
__global__ __launch_bounds__(256) void poolgate_kernel(
    const float* __restrict__ x,
    const float* __restrict__ w1, const float* __restrict__ b1,
    const float* __restrict__ gw1, const float* __restrict__ gb1,
    const float* __restrict__ w2, const float* __restrict__ b2,
    const float* __restrict__ gw2, const float* __restrict__ gb2,
    float* __restrict__ pooled, float* __restrict__ gate,
    int* __restrict__ cnt)   // 32 counters, each on its own 128B line
{
    const int row = blockIdx.x;        // n*C_ + c
    const int n = row >> 9;
    const int tid = threadIdx.x;

    // ---- pool this row ----
    {
        const f4* xr = reinterpret_cast<const f4*>(x + (size_t)row * HW_);
        float acc = 0.f;
        for (int j = tid; j < HW4_; j += 256) {
            f4 v = xr[j];
            acc += (v.x + v.y) + (v.z + v.w);
        }
        for (int o = 32; o; o >>= 1) acc += __shfl_down(acc, o, 64);
        __shared__ float s[4];
        if ((tid & 63) == 0) s[tid >> 6] = acc;
        __syncthreads();
        if (tid == 0)
            ST_A(&pooled[row], (s[0] + s[1] + s[2] + s[3]) * (1.0f / HW_));
    }

    // ---- arrival: relaxed RMW, ordered after the pooled store by vmcnt(0) ----
    __shared__ int lastFlag;
    if (tid == 0) {
        asm volatile("s_waitcnt vmcnt(0)" ::: "memory");  // pooled store complete
        const int old = __hip_atomic_fetch_add(&cnt[n * 32], 1, __ATOMIC_RELAXED,
                                               __HIP_MEMORY_SCOPE_AGENT);
        lastFlag = (old == C_ - 1);
    }
    __syncthreads();
    if (!lastFlag) return;

    // ---- last arrival: compute gate for sample n (256 threads) ----
    __shared__ float sp[C_];
    __shared__ float sh[CR_];
    __shared__ float sred[4];
    const int base = n * C_;
    sp[tid]       = LD_A(&pooled[base + tid]);
    sp[tid + 256] = LD_A(&pooled[base + 256 + tid]);
    __syncthreads();

    // h[r] = dot(sp, w1[r,:]) + b1[r]; 4 threads per r
    {
        const int r = tid >> 2, l4 = tid & 3;
        float a = 0.f;
        for (int cc = l4; cc < C_; cc += 4) a += sp[cc] * w1[r * C_ + cc];
        a += __shfl_xor(a, 1, 64);
        a += __shfl_xor(a, 2, 64);
        if (l4 == 0) sh[r] = a + b1[r];
    }
    __syncthreads();

    // GroupNorm(1) over 64 + ELU (first wave)
    if (tid < 64) {
        const float v = sh[tid];
        float s = v;
        for (int o = 32; o; o >>= 1) s += __shfl_xor(s, o, 64);
        const float mu = s * (1.0f / CR_);
        const float d = v - mu;
        float vv = d * d;
        for (int o = 32; o; o >>= 1) vv += __shfl_xor(vv, o, 64);
        float xn = d * rsqrtf(vv * (1.0f / CR_) + EPS) * gw1[tid] + gb1[tid];
        sh[tid] = xn > 0.f ? xn : expm1f(xn);   // ELU alpha=1
    }
    __syncthreads();

    // g for channels tid, tid+256
    float g0 = b2[tid], g1 = b2[tid + 256];
    #pragma unroll 8
    for (int r = 0; r < CR_; ++r) {
        g0 += sh[r] * w2[tid * CR_ + r];
        g1 += sh[r] * w2[(tid + 256) * CR_ + r];
    }
    // GroupNorm(1) over 512
    float s = g0 + g1;
    for (int o = 32; o; o >>= 1) s += __shfl_xor(s, o, 64);
    if ((tid & 63) == 0) sred[tid >> 6] = s;
    __syncthreads();
    const float mu = (sred[0] + sred[1] + sred[2] + sred[3]) * (1.0f / C_);
    const float d0 = g0 - mu, d1 = g1 - mu;
    float vv = d0 * d0 + d1 * d1;
    for (int o = 32; o; o >>= 1) vv += __shfl_xor(vv, o, 64);
    __syncthreads();
    if ((tid & 63) == 0) sred[tid >> 6] = vv;
    __syncthreads();
    const float rstd = rsqrtf((sred[0] + sred[1] + sred[2] + sred[3]) * (1.0f / C_) + EPS);
    const float xn0 = d0 * rstd * gw2[tid] + gb2[tid];
    const float xn1 = d1 * rstd * gw2[tid + 256] + gb2[tid + 256];
    gate[base + tid]       = 1.f / (1.f + expf(-xn0));
    gate[base + tid + 256] = 1.f / (1.f + expf(-xn1));
}

// ---------------- Kernel B: broadcast scale (r3 body, nt stores restored) ----------------
__global__ __launch_bounds__(256) void scale_kernel(const float* __restrict__ x,
                                                    const float* __restrict__ gate,
                                                    float* __restrict__ out) {
    const int row = blockIdx.x;
    const float g = gate[row];
    const f4* xr = reinterpret_cast<const f4*>(x + (size_t)row * HW_);
    f4* orow = reinterpret_cast<f4*>(out + (size_t)row * HW_);
    for (int j = threadIdx.x; j < HW4_; j += 256) {
        f4 v = xr[j];
        v *= g;
        __builtin_nontemporal_store(v, &orow[j]);
    }
}

extern "C" void kernel_launch(void* const* d_in, const int* in_sizes, int n_in,
                              void* d_out, int out_size, void* d_ws, size_t ws_size,
                              hipStream_t stream) {
    const float* x   = (const float*)d_in[0];
    const float* w1  = (const float*)d_in[1];
    const float* b1  = (const float*)d_in[2];
    const float* gw1 = (const float*)d_in[3];
    const float* gb1 = (const float*)d_in[4];
    const float* w2  = (const float*)d_in[5];
    const float* b2  = (const float*)d_in[6];
    const float* gw2 = (const float*)d_in[7];
    const float* gb2 = (const float*)d_in[8];
    float* out = (float*)d_out;

    float* pooled = (float*)d_ws;              // N_*C_ floats
    float* gate   = pooled + N_ * C_;          // N_*C_ floats
    int*   cnt    = (int*)(gate + N_ * C_);    // 32 * 32 ints (one line each)

    hipMemsetAsync(cnt, 0, N_ * 32 * sizeof(int), stream);

    poolgate_kernel<<<N_ * C_, 256, 0, stream>>>(x, w1, b1, gw1, gb1,
                                                 w2, b2, gw2, gb2,
                                                 pooled, gate, cnt);
    scale_kernel<<<N_ * C_, 256, 0, stream>>>(x, gate, out);
}

// Round 14
// 118.057 us; speedup vs baseline: 1.2450x; 1.2450x over previous
//
#include <hip/hip_runtime.h>
#include <math.h>

#define N_ 32
#define C_ 512
#define CR_ 64
#define HW_ 3136
#define HW4_ 784
constexpr float EPS = 1e-5f;

typedef float f4 __attribute__((ext_vector_type(4)));

#define LD_A(p)   __hip_atomic_load((p), __ATOMIC_RELAXED, __HIP_MEMORY_SCOPE_AGENT)
#define ST_A(p,v) __hip_atomic_store((p), (v), __ATOMIC_RELAXED, __HIP_MEMORY_SCOPE_AGENT)

// ---------------- Kernel 1: global average pool (r3 body, unchanged) ----------------
__global__ __launch_bounds__(256) void pool_kernel(const float* __restrict__ x,
                                                   float* __restrict__ pooled) {
    const int row = blockIdx.x;  // n*C + c
    const f4* xr = reinterpret_cast<const f4*>(x + (size_t)row * HW_);
    float acc = 0.f;
    for (int j = threadIdx.x; j < HW4_; j += 256) {
        f4 v = xr[j];
        acc += (v.x + v.y) + (v.z + v.w);
    }
    for (int o = 32; o; o >>= 1) acc += __shfl_down(acc, o, 64);
    __shared__ float s[4];
    if ((threadIdx.x & 63) == 0) s[threadIdx.x >> 6] = acc;
    __syncthreads();
    if (threadIdx.x == 0) {
        pooled[row] = (s[0] + s[1] + s[2] + s[3]) * (1.0f / HW_);
    }
}

// ---------------- Kernel 2: gate (32 front blocks) + scale (16384 blocks) ----------------
// Gate blocks' input (pooled) is complete at the kernel boundary -> no circular
// dependency; scale blocks' wait terminates after ~4us of front-block work.
__global__ __launch_bounds__(256) void gatescale_kernel(
    const float* __restrict__ x,
    const float* __restrict__ pooled,
    const float* __restrict__ w1, const float* __restrict__ b1,
    const float* __restrict__ gw1, const float* __restrict__ gb1,
    const float* __restrict__ w2, const float* __restrict__ b2,
    const float* __restrict__ gw2, const float* __restrict__ gb2,
    float* __restrict__ gate, int* __restrict__ flag,
    float* __restrict__ out)
{
    const int bid = blockIdx.x;
    const int tid = threadIdx.x;

    if (bid < N_) {
        // ---- gate for sample n (256 threads) ----
        const int n = bid;
        __shared__ float sp[C_];
        __shared__ float sh[CR_];
        __shared__ float sred[4];
        const int base = n * C_;
        sp[tid]       = pooled[base + tid];
        sp[tid + 256] = pooled[base + 256 + tid];
        __syncthreads();

        // h[r] = dot(sp, w1[r,:]) + b1[r]; 4 threads per r
        {
            const int r = tid >> 2, l4 = tid & 3;
            float a = 0.f;
            for (int cc = l4; cc < C_; cc += 4) a += sp[cc] * w1[r * C_ + cc];
            a += __shfl_xor(a, 1, 64);
            a += __shfl_xor(a, 2, 64);
            if (l4 == 0) sh[r] = a + b1[r];
        }
        __syncthreads();

        // GroupNorm(1) over 64 + ELU (first wave)
        if (tid < 64) {
            const float v = sh[tid];
            float s = v;
            for (int o = 32; o; o >>= 1) s += __shfl_xor(s, o, 64);
            const float mu = s * (1.0f / CR_);
            const float d = v - mu;
            float vv = d * d;
            for (int o = 32; o; o >>= 1) vv += __shfl_xor(vv, o, 64);
            float xn = d * rsqrtf(vv * (1.0f / CR_) + EPS) * gw1[tid] + gb1[tid];
            sh[tid] = xn > 0.f ? xn : expm1f(xn);   // ELU alpha=1
        }
        __syncthreads();

        // g for channels tid, tid+256
        float g0 = b2[tid], g1 = b2[tid + 256];
        #pragma unroll 8
        for (int r = 0; r < CR_; ++r) {
            g0 += sh[r] * w2[tid * CR_ + r];
            g1 += sh[r] * w2[(tid + 256) * CR_ + r];
        }
        // GroupNorm(1) over 512
        float s = g0 + g1;
        for (int o = 32; o; o >>= 1) s += __shfl_xor(s, o, 64);
        if ((tid & 63) == 0) sred[tid >> 6] = s;
        __syncthreads();
        const float mu = (sred[0] + sred[1] + sred[2] + sred[3]) * (1.0f / C_);
        const float d0 = g0 - mu, d1 = g1 - mu;
        float vv = d0 * d0 + d1 * d1;
        for (int o = 32; o; o >>= 1) vv += __shfl_xor(vv, o, 64);
        __syncthreads();
        if ((tid & 63) == 0) sred[tid >> 6] = vv;
        __syncthreads();
        const float rstd = rsqrtf((sred[0] + sred[1] + sred[2] + sred[3]) * (1.0f / C_) + EPS);
        const float xn0 = d0 * rstd * gw2[tid] + gb2[tid];
        const float xn1 = d1 * rstd * gw2[tid + 256] + gb2[tid + 256];
        ST_A(&gate[base + tid],       1.f / (1.f + expf(-xn0)));
        ST_A(&gate[base + tid + 256], 1.f / (1.f + expf(-xn1)));
        // release the flag only after the gate stores have completed
        if (tid == 0) {
            asm volatile("s_waitcnt vmcnt(0)" ::: "memory");
            ST_A(&flag[n * 32], 1);
        }
        return;
    }

    // ---- scale one row ----
    const int row = bid - N_;          // n*C_ + c
    const int n = row >> 9;
    const f4* xr = reinterpret_cast<const f4*>(x + (size_t)row * HW_);
    f4* orow = reinterpret_cast<f4*>(out + (size_t)row * HW_);

    // issue the row loads first; they fly while we wait for the flag
    f4 v0 = xr[tid];
    f4 v1 = xr[tid + 256];
    f4 v2 = xr[tid + 512];
    f4 v3;
    const bool has4 = tid < (HW4_ - 768);
    if (has4) v3 = xr[tid + 768];

    if (tid == 0) {
        while (LD_A(&flag[n * 32]) == 0) __builtin_amdgcn_s_sleep(8);
    }
    __syncthreads();

    const float g = LD_A(&gate[row]);
    v0 *= g; v1 *= g; v2 *= g;
    __builtin_nontemporal_store(v0, &orow[tid]);
    __builtin_nontemporal_store(v1, &orow[tid + 256]);
    __builtin_nontemporal_store(v2, &orow[tid + 512]);
    if (has4) { v3 *= g; __builtin_nontemporal_store(v3, &orow[tid + 768]); }
}

extern "C" void kernel_launch(void* const* d_in, const int* in_sizes, int n_in,
                              void* d_out, int out_size, void* d_ws, size_t ws_size,
                              hipStream_t stream) {
    const float* x   = (const float*)d_in[0];
    const float* w1  = (const float*)d_in[1];
    const float* b1  = (const float*)d_in[2];
    const float* gw1 = (const float*)d_in[3];
    const float* gb1 = (const float*)d_in[4];
    const float* w2  = (const float*)d_in[5];
    const float* b2  = (const float*)d_in[6];
    const float* gw2 = (const float*)d_in[7];
    const float* gb2 = (const float*)d_in[8];
    float* out = (float*)d_out;

    float* pooled = (float*)d_ws;              // N_*C_ floats
    float* gate   = pooled + N_ * C_;          // N_*C_ floats
    int*   flag   = (int*)(gate + N_ * C_);    // 32 * 32 ints (one line each)

    hipMemsetAsync(flag, 0, N_ * 32 * sizeof(int), stream);

    pool_kernel<<<N_ * C_, 256, 0, stream>>>(x, pooled);
    gatescale_kernel<<<N_ + N_ * C_, 256, 0, stream>>>(
        x, pooled, w1, b1, gw1, gb1, w2, b2, gw2, gb2, gate, flag, out);
}